// Round 1
// baseline (359.960 us; speedup 1.0000x reference)
//
#include <hip/hip_runtime.h>
#include <stdint.h>

typedef unsigned long long u64;
typedef float vf4 __attribute__((ext_vector_type(4)));

#define NB 32
#define N 512
#define MAXD 10
#define NW 8  // u64 words per 512-bit row

// ---------------- K1: binarize + symmetrize + mask -> packed bitset ----------------
// grid: (36 tile-pairs, B), block 256. Tiles 64x64; __ballot builds one u64 word per row.
// NOTE: node_mask arrives as int32 (harness converts jnp bool -> int).
__global__ __launch_bounds__(256) void k1_pack(const float* __restrict__ adj,
                                               const int* __restrict__ mask,
                                               u64* __restrict__ gsym) {
    __shared__ float ldsA[64 * 65];  // +1 pad: row & column reads both conflict-free
    __shared__ float ldsB[64 * 65];
    __shared__ unsigned char mI[64], mJ[64];
    int p = blockIdx.x;
    int b = blockIdx.y;
    int ti = 0;
    while (p >= 8 - ti) { p -= 8 - ti; ++ti; }
    int tj = ti + p;
    int i0 = ti * 64, j0 = tj * 64;
    int t = threadIdx.x;
    if (t < 64) mI[t] = (mask[b * N + i0 + t] != 0);
    else if (t < 128) mJ[t - 64] = (mask[b * N + j0 + (t - 64)] != 0);
    const float* Ab = adj + (size_t)b * N * N;
    #pragma unroll
    for (int s = 0; s < 4; ++s) {
        int idx = t + 256 * s;          // 0..1023 float4 slots
        int r = idx >> 4, c4 = idx & 15;
        float4 va = *(const float4*)&Ab[(size_t)(i0 + r) * N + j0 + c4 * 4];
        float4 vb = *(const float4*)&Ab[(size_t)(j0 + r) * N + i0 + c4 * 4];
        int o = r * 65 + c4 * 4;
        ldsA[o] = va.x; ldsA[o + 1] = va.y; ldsA[o + 2] = va.z; ldsA[o + 3] = va.w;
        ldsB[o] = vb.x; ldsB[o + 1] = vb.y; ldsB[o + 2] = vb.z; ldsB[o + 3] = vb.w;
    }
    __syncthreads();
    int wave = t >> 6, lane = t & 63;
    // rows of tile ti, word tj
    for (int s = 0; s < 16; ++s) {
        int r = wave * 16 + s;
        bool bit = ((ldsA[r * 65 + lane] > 0.5f) || (ldsB[lane * 65 + r] > 0.5f))
                   && mI[r] && mJ[lane];
        u64 word = __ballot(bit);
        if (lane == 0) gsym[((size_t)b * N + i0 + r) * NW + tj] = word;
    }
    // rows of tile tj, word ti (diagonal tiles: benign identical double write)
    for (int s = 0; s < 16; ++s) {
        int r = wave * 16 + s;
        bool bit = ((ldsB[r * 65 + lane] > 0.5f) || (ldsA[lane * 65 + r] > 0.5f))
                   && mJ[r] && mI[lane];
        u64 word = __ballot(bit);
        if (lane == 0) gsym[((size_t)b * N + j0 + r) * NW + ti] = word;
    }
}

// spread 8 bits -> u64 of 8 bytes each 0/1
__device__ __forceinline__ u64 spread8(unsigned b) {
    u64 x = (u64)(b * 0x01010101u);
    x |= x << 32;                       // broadcast byte to all 8 byte lanes
    x &= 0x8040201008040201ULL;         // byte i keeps bit i
    x += 0x7f7f7f7f7f7f7f7fULL;         // bit7 of byte i = (bit i was set); no cross-byte carry
    return (x >> 7) & 0x0101010101010101ULL;
}

// ---------------- K2: bitset-BFS -> dist bytes in global ws ----------------
// grid: B*8 blocks, 256 threads. Wave 0 runs 64 per-source-row BFS with bit-sliced
// 4-bit distance counters; dist bytes staged in LDS; then all 4 waves store the
// 32 KB dist-byte slab coalesced. Decoupled from expansion so the 256 MiB stream
// can run at high occupancy in K3 instead of 1 wave/SIMD here.
__global__ __launch_bounds__(256) void k2_bfs(const u64* __restrict__ gsym,
                                              const int* __restrict__ mask,
                                              u64* __restrict__ distw) {
    __shared__ u64 adjT[NW * N];      // 32 KB, plane-major [w][j]: 4-way aliasing only
    __shared__ u64 outB[64 * 65];     // packed dist bytes, pad 65 breaks stride-128
    int blk = blockIdx.x;
    int b = blk >> 3;
    int r0 = (blk & 7) * 64;
    int t = threadIdx.x;
    const u64* gs = gsym + (size_t)b * N * NW;
    for (int q = t; q < N * NW; q += 256) {
        u64 w = gs[q];                           // coalesced global read
        adjT[(q & 7) * N + (q >> 3)] = w;        // transpose to plane-major
    }
    __syncthreads();

    if (t < 64) {
        int i = r0 + t;
        bool mi = mask[b * N + i] != 0;
        u64 c0[NW], c1[NW], c2[NW], c3[NW];
        #pragma unroll
        for (int w = 0; w < NW; ++w) { c0[w] = 0; c1[w] = 0; c2[w] = 0; c3[w] = 0; }

        if (mi) {
            u64 reach[NW] = {};
            u64 frontier[NW] = {};
            reach[i >> 6] = 1ULL << (i & 63);
            #pragma unroll
            for (int w = 0; w < NW; ++w) frontier[w] = reach[w];
            bool active = true;
            for (int k = 0; k <= MAXD; ++k) {
                // c += ~reach  (bit-sliced increment, 4-bit, max value 11)
                #pragma unroll
                for (int w = 0; w < NW; ++w) {
                    u64 u = ~reach[w];
                    u64 t0 = c0[w] & u; c0[w] ^= u;
                    u64 t1 = c1[w] & t0; c1[w] ^= t0;
                    u64 t2 = c2[w] & t1; c2[w] ^= t1;
                    c3[w] ^= t2;
                }
                if (k == MAXD) break;
                if (active) {
                    u64 acc[NW] = {};
                    bool sat = false;
                    for (int w = 0; w < NW && !sat; ++w) {
                        u64 f = frontier[w];
                        while (f) {
                            int j = (w << 6) + __builtin_ctzll(f);
                            f &= f - 1;
                            #pragma unroll
                            for (int e = 0; e < NW; ++e) acc[e] |= adjT[e * N + j];
                            u64 all = acc[0];
                            #pragma unroll
                            for (int e = 1; e < NW; ++e) all &= acc[e];
                            if (all == ~0ULL) { sat = true; break; }  // union saturated: exact
                        }
                    }
                    bool any = false;
                    #pragma unroll
                    for (int w = 0; w < NW; ++w) {
                        u64 nf = acc[w] & ~reach[w];
                        frontier[w] = nf;
                        reach[w] |= nf;
                        any = any || (nf != 0);
                    }
                    active = any;
                }
            }
        } else {
            // invalid source row: all distances = 11 = 0b1011
            #pragma unroll
            for (int w = 0; w < NW; ++w) { c0[w] = ~0ULL; c1[w] = ~0ULL; c3[w] = ~0ULL; }
        }

        // expand bit-sliced counters -> dist bytes (8 per u64) into LDS
        #pragma unroll
        for (int w = 0; w < NW; ++w) {
            #pragma unroll
            for (int h = 0; h < 8; ++h) {
                unsigned b0 = (unsigned)(c0[w] >> (8 * h)) & 0xFF;
                unsigned b1 = (unsigned)(c1[w] >> (8 * h)) & 0xFF;
                unsigned b2 = (unsigned)(c2[w] >> (8 * h)) & 0xFF;
                unsigned b3 = (unsigned)(c3[w] >> (8 * h)) & 0xFF;
                outB[t * 65 + w * 8 + h] =
                    spread8(b0) | (spread8(b1) << 1) | (spread8(b2) << 2) | (spread8(b3) << 3);
            }
        }
    }
    __syncthreads();

    // all 4 waves: store 64 rows x 64 u64 of dist bytes, fully coalesced
    u64* dp = distw + ((size_t)(b * N + r0)) * 64;  // 64 u64 words per 512-byte row
    for (int q = t; q < 64 * 64; q += 256) {
        dp[q] = outB[(q >> 6) * 65 + (q & 63)];
    }
}

// ---------------- K3: pure streaming expansion dist byte -> 2x vf4 ----------------
// grid 2048 x 256, grid-stride. LDS = 384 B table only -> high occupancy; the
// ubyte-load -> ds_read_b128 -> store chain is hidden by TLP. Stores are
// lane-consecutive 16B (perfect coalescing). Plain stores (prior A/B: nt hurt).
__global__ __launch_bounds__(256) void k3_expand(const u64* __restrict__ distw,
                                                 const float* __restrict__ emb,
                                                 vf4* __restrict__ out4) {
    __shared__ vf4 e4[(MAXD + 2) * 2];
    int t = threadIdx.x;
    if (t < (MAXD + 2) * 2) e4[t] = ((const vf4*)emb)[t];
    __syncthreads();
    const unsigned char* __restrict__ db = (const unsigned char*)distw;
    const size_t total = (size_t)NB * N * N * 2;        // vf4 count = 16.78M
    const size_t stride = (size_t)gridDim.x * 256;
    for (size_t q = (size_t)blockIdx.x * 256 + t; q < total; q += stride) {
        int d = db[q >> 1];          // dist byte [b][i][j]; L2-resident (8 MiB)
        out4[q] = e4[d * 2 + (int)(q & 1)];
    }
}

extern "C" void kernel_launch(void* const* d_in, const int* in_sizes, int n_in,
                              void* d_out, int out_size, void* d_ws, size_t ws_size,
                              hipStream_t stream) {
    const float* adj = (const float*)d_in[0];
    const int* mask = (const int*)d_in[1];  // jnp bool -> int32 per harness convention
    const float* emb = (const float*)d_in[2];
    // workspace layout: [0, 8 MiB) dist bytes, [8 MiB, 9 MiB) packed adjacency bitset
    u64* distw = (u64*)d_ws;
    u64* gsym = (u64*)((char*)d_ws + (size_t)NB * N * N);  // 8 MiB offset
    k1_pack<<<dim3(36, NB), 256, 0, stream>>>(adj, mask, gsym);
    k2_bfs<<<dim3(NB * 8), 256, 0, stream>>>(gsym, mask, distw);
    k3_expand<<<dim3(2048), 256, 0, stream>>>(distw, emb, (vf4*)d_out);
}